// Round 6
// baseline (523.853 us; speedup 1.0000x reference)
//
#include <hip/hip_runtime.h>
#include <math.h>

// BlockwiseEarlyExitMamba: B=128, L=64, EXIT_POS=32 -> only t<32 matter.
// v7: 1024-thread (16-wave, 4 waves/SIMD) per-batch mega-kernel.
// __launch_bounds__(1024, 4) pins VGPR cap at 128 (v3 failed because the
// compiler chose 64). Phase numerics identical to v6 (absmax 0.0):
// sz-in-regs scan, u from packed LDS, chunked scan transients, inline gate.
#define BATCH 128

using bf16x8 = __attribute__((ext_vector_type(8))) short;
using f32x4  = __attribute__((ext_vector_type(4))) float;
typedef unsigned short ushort_t;
typedef unsigned int   uint_t;

__device__ __forceinline__ float silu_f(float x) { return x / (1.f + __expf(-x)); }

__device__ __forceinline__ ushort_t bf16_rne(float f) {
  unsigned int u = __float_as_uint(f);
  u += 0x7FFFu + ((u >> 16) & 1u);
  return (ushort_t)(u >> 16);
}
__device__ __forceinline__ float bf16_to_f(ushort_t h) {
  return __uint_as_float(((unsigned int)h) << 16);
}
__device__ __forceinline__ void bf16_split(float f, ushort_t& hi, ushort_t& lo) {
  hi = bf16_rne(f);
  lo = bf16_rne(f - bf16_to_f(hi));
}

// split-bf16 3-MFMA: (ah+al)*(wh+wl) ~= ah*wh + ah*wl + al*wh  (al*wl negligible)
__device__ __forceinline__ f32x4 mfma3(bf16x8 ah, bf16x8 al, bf16x8 wh, bf16x8 wl, f32x4 acc) {
  acc = __builtin_amdgcn_mfma_f32_16x16x32_bf16(ah, wh, acc, 0, 0, 0);
  acc = __builtin_amdgcn_mfma_f32_16x16x32_bf16(ah, wl, acc, 0, 0, 0);
  acc = __builtin_amdgcn_mfma_f32_16x16x32_bf16(al, wh, acc, 0, 0, 0);
  return acc;
}

// ---------------- merged weight prep: fp32 -> hi/lo bf16 ----------------
#define NIP (4*1024*256)     // in_proj
#define NOP (4*256*512)      // out_proj
#define NXP (4*64*512)       // xproj padded 48->64 rows
#define NFW (256*160)        // fusion_w padded 136->160 cols
#define NPREP (NIP+NOP+NXP+NFW)   // 1744896 = 6816*256
__global__ __launch_bounds__(256) void prep_w(
    const float* __restrict__ ipw, const float* __restrict__ opw,
    const float* __restrict__ xpw, const float* __restrict__ fw,
    ushort_t* __restrict__ ih, ushort_t* __restrict__ il,
    ushort_t* __restrict__ oh, ushort_t* __restrict__ ol,
    ushort_t* __restrict__ xh, ushort_t* __restrict__ xl,
    ushort_t* __restrict__ fh, ushort_t* __restrict__ fl) {
  int i = blockIdx.x*256 + threadIdx.x;
  float v; ushort_t h, l;
  if (i < NIP) {
    v = ipw[i]; bf16_split(v, h, l); ih[i] = h; il[i] = l;
  } else if (i < NIP+NOP) {
    int j = i - NIP;
    v = opw[j]; bf16_split(v, h, l); oh[j] = h; ol[j] = l;
  } else if (i < NIP+NOP+NXP) {
    int j = i - (NIP+NOP);
    int lay = j >> 15;            // 64*512 = 32768
    int r = (j >> 9) & 63, c = j & 511;
    v = (r < 48) ? xpw[(size_t)lay*48*512 + r*512 + c] : 0.f;
    bf16_split(v, h, l); xh[j] = h; xl[j] = l;
  } else {
    int j = i - (NIP+NOP+NXP);
    int r = j / 160, c = j - r*160;
    v = (c < 136) ? fw[r*136 + c] : 0.f;
    bf16_split(v, h, l); fh[j] = h; fl[j] = l;
  }
}

// ---------------- LDS layout (bytes) ----------------
// A: sF32 f32 [32][260]                      33280   (residual feat, persistent)
// B: sFh/sFl us [32][264] x2                 33792   (feat hi/lo; aliased: sT2 f32 [32][260],
//                                                     sDbc f32 4x[32][64], sHid f32[128])
// C: sZT f32 [32][524]                       67072   (z then pre-conv u staging; aliased:
//                                                     sUh/sUl us [32][520] x2 (u then y),
//                                                     catH/catL us [32][168] x2)
#define OFF_A 0
#define OFF_B 33280
#define OFF_C 67072
#define SMEM_TOTAL 134144

// LN of a [32][256] tile; 32 threads/row, 8 cols each (1024 threads).
// Reads sIn (+resid +addv); internal barrier; writes sF32o + hi/lo bf16.
__device__ __forceinline__ void ln_block(
    const float* sIn, const float* resid, const float* addv,
    const float* __restrict__ g, const float* __restrict__ bb,
    float* sF32o, ushort_t* sFho, ushort_t* sFlo, int tid) {
  int row = tid >> 5, sub = tid & 31;
  float v[8];
  float s = 0.f;
  #pragma unroll
  for (int i = 0; i < 8; ++i) {
    int c = sub + 32*i;
    float t = sIn[row*260 + c];
    if (resid) t += resid[row*260 + c];
    if (addv)  t += addv[c];
    v[i] = t; s += t;
  }
  s += __shfl_xor(s, 1); s += __shfl_xor(s, 2); s += __shfl_xor(s, 4);
  s += __shfl_xor(s, 8); s += __shfl_xor(s, 16);
  float mu = s * (1.f/256.f);
  float s2 = 0.f;
  #pragma unroll
  for (int i = 0; i < 8; ++i) { float dv = v[i]-mu; s2 += dv*dv; }
  s2 += __shfl_xor(s2, 1); s2 += __shfl_xor(s2, 2); s2 += __shfl_xor(s2, 4);
  s2 += __shfl_xor(s2, 8); s2 += __shfl_xor(s2, 16);
  float rs = rsqrtf(s2*(1.f/256.f) + 1e-5f);
  __syncthreads();              // sIn aliases sFho/sFlo: read-before, write-after
  #pragma unroll
  for (int i = 0; i < 8; ++i) {
    int c = sub + 32*i;
    float o = (v[i]-mu)*rs*g[c] + bb[c];
    sF32o[row*260 + c] = o;
    ushort_t hh, ll; bf16_split(o, hh, ll);
    sFho[row*264 + c] = hh;
    sFlo[row*264 + c] = ll;
  }
}

// ---------------- mega kernel: tokenizer + 4 layers + classifier ----------
__global__ __launch_bounds__(1024, 4) void mega_kernel(
    const float* __restrict__ x,
    const float* __restrict__ ep, const float* __restrict__ ef, const float* __restrict__ ed,
    const float* __restrict__ plw, const float* __restrict__ plb,
    const float* __restrict__ piw, const float* __restrict__ pib,
    const ushort_t* __restrict__ fw_h, const ushort_t* __restrict__ fw_l,
    const float* __restrict__ fb,
    const float* __restrict__ tng, const float* __restrict__ tnb,
    const ushort_t* __restrict__ ipw_h, const ushort_t* __restrict__ ipw_l,
    const float* __restrict__ cw, const float* __restrict__ cb,
    const ushort_t* __restrict__ xpw_h, const ushort_t* __restrict__ xpw_l,
    const float* __restrict__ dpw, const float* __restrict__ dpb,
    const float* __restrict__ alog, const float* __restrict__ dsk,
    const ushort_t* __restrict__ opw_h, const ushort_t* __restrict__ opw_l,
    const float* __restrict__ lng, const float* __restrict__ lnb,
    const float* __restrict__ w1, const float* __restrict__ b1,
    const float* __restrict__ w2, const float* __restrict__ b2,
    float* __restrict__ out) {
  extern __shared__ __align__(16) char sm[];
  float*    sF32 = (float*)(sm + OFF_A);       // [32][260]
  ushort_t* sFh  = (ushort_t*)(sm + OFF_B);    // [32][264]
  ushort_t* sFl  = sFh + 32*264;
  float*    sT2  = (float*)(sm + OFF_B);       // [32][260] GEMM frag dump
  float*    sDbc = (float*)(sm + OFF_B);       // 4 x [32][64] xproj partials
  float*    sHid = (float*)(sm + OFF_B);       // [128]
  float*    sZT  = (float*)(sm + OFF_C);       // [32][524] f32 z / pre-conv u
  ushort_t* sUh  = (ushort_t*)(sm + OFF_C);    // [32][520] u hi -> y hi
  ushort_t* sUl  = sUh + 32*520;               //           u lo -> y lo
  ushort_t* catH = (ushort_t*)(sm + OFF_C);    // [32][168]
  ushort_t* catL = catH + 32*168;

  const int tid  = threadIdx.x;
  const int b    = blockIdx.x;
  const int wave = tid >> 6, lane = tid & 63;
  const int lm   = lane & 15, lq = lane >> 4;
  const int d    = tid & 511;                  // channel (conv/scan threads)
  const int hv   = tid >> 9;                   // 0/1 thread half

  // ================= tokenizer =================
  {
    int r = tid >> 5, cl = tid & 31;
    const float* xr = x + ((size_t)b*64 + r)*5;   // L=64 stride in input
    float x0 = xr[0], x1 = xr[1], x2 = xr[2], x3 = xr[3], x4 = xr[4];
    int proto = min(max((int)x0, 0), 255);
    int flags = min(max((int)x2, 0), 63);
    int direc = min(max((int)x4, 0), 1);
    #pragma unroll
    for (int j = 0; j < 5; ++j) {
      int c = cl + 32*j;
      float v;
      if (c < 32)       v = ep[proto*32 + c];
      else if (c < 64)  v = x1*plw[c-32] + plb[c-32];
      else if (c < 96)  v = ef[flags*32 + (c-64)];
      else if (c < 128) v = x3*piw[c-96] + pib[c-96];
      else if (c < 136) v = ed[direc*8 + (c-128)];
      else              v = 0.f;
      ushort_t hh, ll; bf16_split(v, hh, ll);
      catH[r*168 + c] = hh;
      catL[r*168 + c] = ll;
    }
  }
  __syncthreads();
  // fusion GEMM: pre = cat @ fw^T (M=32, N=256, K=160); 16 waves x 16 cols
  {
    f32x4 acc[2] = {(f32x4){0.f,0.f,0.f,0.f}, (f32x4){0.f,0.f,0.f,0.f}};
    int nb = wave*16;
    const ushort_t* wh0 = fw_h + (size_t)(nb+lm)*160 + lq*8;
    const ushort_t* wl0 = fw_l + (size_t)(nb+lm)*160 + lq*8;
    for (int k0 = 0; k0 < 160; k0 += 32) {
      bf16x8 cwh = *(const bf16x8*)(wh0 + k0);
      bf16x8 cwl = *(const bf16x8*)(wl0 + k0);
      #pragma unroll
      for (int mi = 0; mi < 2; ++mi) {
        bf16x8 ah = *(const bf16x8*)(catH + (mi*16+lm)*168 + k0 + lq*8);
        bf16x8 al = *(const bf16x8*)(catL + (mi*16+lm)*168 + k0 + lq*8);
        acc[mi] = mfma3(ah, al, cwh, cwl, acc[mi]);
      }
    }
    #pragma unroll
    for (int mi = 0; mi < 2; ++mi)
      #pragma unroll
      for (int r2 = 0; r2 < 4; ++r2)
        sT2[(mi*16 + lq*4 + r2)*260 + nb + lm] = acc[mi][r2];
  }
  __syncthreads();
  ln_block(sT2, nullptr, fb, tng, tnb, sF32, sFh, sFl, tid);
  __syncthreads();

  // ================= 4 mamba layers =================
  #pragma unroll 1
  for (int l = 0; l < 4; ++l) {
    const ushort_t* iph = ipw_h + (size_t)l*1024*256;
    const ushort_t* ipl2= ipw_l + (size_t)l*1024*256;
    const ushort_t* xph = xpw_h + (size_t)l*64*512;
    const ushort_t* xpl = xpw_l + (size_t)l*64*512;
    const ushort_t* oph = opw_h + (size_t)l*256*512;
    const ushort_t* opl = opw_l + (size_t)l*256*512;
    float sz[32];

    // ---- Z pass: z = feat @ ipw[512:1024]^T ; 16 waves x 32 cols ----
    {
      f32x4 acc[2][2];
      #pragma unroll
      for (int mi = 0; mi < 2; ++mi)
        #pragma unroll
        for (int nt = 0; nt < 2; ++nt) acc[mi][nt] = (f32x4){0.f,0.f,0.f,0.f};
      int rowbase = 512 + wave*32;
      for (int k0 = 0; k0 < 256; k0 += 32) {
        bf16x8 fAh[2], fAl[2];
        #pragma unroll
        for (int mi = 0; mi < 2; ++mi) {
          int rr = mi*16 + lm;
          fAh[mi] = *(const bf16x8*)(sFh + rr*264 + k0 + lq*8);
          fAl[mi] = *(const bf16x8*)(sFl + rr*264 + k0 + lq*8);
        }
        #pragma unroll
        for (int nt = 0; nt < 2; ++nt) {
          int row = rowbase + nt*16 + lm;
          bf16x8 wh = *(const bf16x8*)(iph + (size_t)row*256 + k0 + lq*8);
          bf16x8 wl = *(const bf16x8*)(ipl2 + (size_t)row*256 + k0 + lq*8);
          #pragma unroll
          for (int mi = 0; mi < 2; ++mi) acc[mi][nt] = mfma3(fAh[mi], fAl[mi], wh, wl, acc[mi][nt]);
        }
      }
      __syncthreads();     // prior readers of C region done
      int nb = wave*32;
      #pragma unroll
      for (int mi = 0; mi < 2; ++mi)
        #pragma unroll
        for (int nt = 0; nt < 2; ++nt)
          #pragma unroll
          for (int r2 = 0; r2 < 4; ++r2)
            sZT[(mi*16 + lq*4 + r2)*524 + nb + nt*16 + lm] = acc[mi][nt][r2];
      __syncthreads();
      if (tid < 512) {
        #pragma unroll
        for (int t = 0; t < 32; ++t) sz[t] = silu_f(sZT[t*524 + d]);
      }
      __syncthreads();
    }

    // ---- U pass: u_pre = feat @ ipw[0:512]^T -> sZT ----
    {
      f32x4 acc[2][2];
      #pragma unroll
      for (int mi = 0; mi < 2; ++mi)
        #pragma unroll
        for (int nt = 0; nt < 2; ++nt) acc[mi][nt] = (f32x4){0.f,0.f,0.f,0.f};
      int rowbase = wave*32;
      for (int k0 = 0; k0 < 256; k0 += 32) {
        bf16x8 fAh[2], fAl[2];
        #pragma unroll
        for (int mi = 0; mi < 2; ++mi) {
          int rr = mi*16 + lm;
          fAh[mi] = *(const bf16x8*)(sFh + rr*264 + k0 + lq*8);
          fAl[mi] = *(const bf16x8*)(sFl + rr*264 + k0 + lq*8);
        }
        #pragma unroll
        for (int nt = 0; nt < 2; ++nt) {
          int row = rowbase + nt*16 + lm;
          bf16x8 wh = *(const bf16x8*)(iph + (size_t)row*256 + k0 + lq*8);
          bf16x8 wl = *(const bf16x8*)(ipl2 + (size_t)row*256 + k0 + lq*8);
          #pragma unroll
          for (int mi = 0; mi < 2; ++mi) acc[mi][nt] = mfma3(fAh[mi], fAl[mi], wh, wl, acc[mi][nt]);
        }
      }
      // sZT readers finished at the barrier ending the Z pass -> safe to overwrite
      int nb = wave*32;
      #pragma unroll
      for (int mi = 0; mi < 2; ++mi)
        #pragma unroll
        for (int nt = 0; nt < 2; ++nt)
          #pragma unroll
          for (int r2 = 0; r2 < 4; ++r2)
            sZT[(mi*16 + lq*4 + r2)*524 + nb + nt*16 + lm] = acc[mi][nt][r2];
    }
    __syncthreads();

    // ---- conv + silu: (d, half) owns 16 t-steps; reg window then packed write ----
    {
      float xw[19];
      int h16 = hv*16;
      #pragma unroll
      for (int j = 0; j < 19; ++j) {
        int gt = h16 + j - 3;
        xw[j] = (gt >= 0) ? sZT[gt*524 + d] : 0.f;
      }
      __syncthreads();    // all sZT reads done before packed overwrite
      const float* cwl2 = cw + (size_t)l*2048 + (size_t)d*4;
      float w0 = cwl2[0], w1c = cwl2[1], w2c = cwl2[2], w3 = cwl2[3];
      float bias = cb[l*512 + d];
      #pragma unroll
      for (int tt = 0; tt < 16; ++tt) {
        float a = bias + w0*xw[tt] + w1c*xw[tt+1] + w2c*xw[tt+2] + w3*xw[tt+3];
        float uv = silu_f(a);
        ushort_t hh, ll; bf16_split(uv, hh, ll);
        sUh[(h16+tt)*520 + d] = hh;
        sUl[(h16+tt)*520 + d] = ll;
      }
    }
    __syncthreads();

    // ---- xproj: 16 waves = 4 row-groups x 4 K-quarters, partials in LDS ----
    {
      int wg = wave & 3, kh = wave >> 2;
      f32x4 acx[2] = {(f32x4){0.f,0.f,0.f,0.f}, (f32x4){0.f,0.f,0.f,0.f}};
      const ushort_t* wh0 = xph + (size_t)(wg*16+lm)*512 + kh*128 + lq*8;
      const ushort_t* wl0 = xpl + (size_t)(wg*16+lm)*512 + kh*128 + lq*8;
      for (int k0 = 0; k0 < 128; k0 += 32) {
        bf16x8 cwh = *(const bf16x8*)(wh0 + k0);
        bf16x8 cwl = *(const bf16x8*)(wl0 + k0);
        #pragma unroll
        for (int mi = 0; mi < 2; ++mi) {
          bf16x8 ah = *(const bf16x8*)(sUh + (mi*16+lm)*520 + kh*128 + k0 + lq*8);
          bf16x8 al = *(const bf16x8*)(sUl + (mi*16+lm)*520 + kh*128 + k0 + lq*8);
          acx[mi] = mfma3(ah, al, cwh, cwl, acx[mi]);
        }
      }
      float* dst = sDbc + kh*2048;
      #pragma unroll
      for (int mi = 0; mi < 2; ++mi)
        #pragma unroll
        for (int r2 = 0; r2 < 4; ++r2)
          dst[(mi*16 + lq*4 + r2)*64 + wg*16 + lm] = acx[mi][r2];
    }
    __syncthreads();
    {
      int i0 = tid*2;
      #pragma unroll
      for (int j = 0; j < 2; ++j) {
        int i = i0 + j;
        sDbc[i] += sDbc[2048+i] + sDbc[4096+i] + sDbc[6144+i];
      }
    }
    __syncthreads();

    // ---- dtproj + selective scan + gate (threads 0..511); y -> sUh/sUl ----
    if (tid < 512) {
      const float* dpwl = dpw + (size_t)l*8192 + (size_t)d*16;
      f32x4 wv[4];
      #pragma unroll
      for (int k = 0; k < 4; ++k) wv[k] = *(const f32x4*)(dpwl + 4*k);
      const float* al2 = alog + (size_t)l*8192 + (size_t)d*16;
      float cc[16], hh2[16];
      #pragma unroll
      for (int n = 0; n < 16; ++n) {
        cc[n] = -__expf(al2[n]) * 1.44269504f;
        hh2[n] = 0.f;
      }
      float bias = dpb[l*512 + d], dskv = dsk[l*512 + d];
      #pragma unroll
      for (int t = 0; t < 32; ++t) {
        const float* rowp = sDbc + t*64;
        float raw = bias;
        #pragma unroll
        for (int k = 0; k < 4; ++k) {
          f32x4 rd = *(const f32x4*)(rowp + 4*k);
          raw += wv[k][0]*rd[0] + wv[k][1]*rd[1] + wv[k][2]*rd[2] + wv[k][3]*rd[3];
        }
        float dtv = (raw > 20.f) ? raw : __logf(1.f + __expf(raw));
        int ui = t*520 + d;
        float uv = bf16_to_f(sUh[ui]) + bf16_to_f(sUl[ui]);
        float du = dtv * uv;
        float yv = 0.f;
        #pragma unroll
        for (int k = 0; k < 4; ++k) {
          f32x4 rb = *(const f32x4*)(rowp + 16 + 4*k);
          f32x4 rc = *(const f32x4*)(rowp + 32 + 4*k);
          #pragma unroll
          for (int j = 0; j < 4; ++j) {
            int n = 4*k + j;
            float en = exp2f(dtv * cc[n]);
            hh2[n] = en*hh2[n] + du*rb[j];
            yv += hh2[n]*rc[j];
          }
        }
        float yg = (yv + uv*dskv) * sz[t];
        ushort_t hh, ll; bf16_split(yg, hh, ll);
        sUh[ui] = hh;     // own-column in-place overwrite (u consumed this iter)
        sUl[ui] = ll;
      }
    }
    __syncthreads();

    // ---- out_proj (256 x 512): 16 waves x 16 cols ----
    {
      f32x4 ao[2] = {(f32x4){0.f,0.f,0.f,0.f}, (f32x4){0.f,0.f,0.f,0.f}};
      const ushort_t* wh0 = oph + (size_t)(wave*16+lm)*512 + lq*8;
      const ushort_t* wl0 = opl + (size_t)(wave*16+lm)*512 + lq*8;
      for (int k0 = 0; k0 < 512; k0 += 32) {
        bf16x8 cwh = *(const bf16x8*)(wh0 + k0);
        bf16x8 cwl = *(const bf16x8*)(wl0 + k0);
        #pragma unroll
        for (int mi = 0; mi < 2; ++mi) {
          bf16x8 yh = *(const bf16x8*)(sUh + (mi*16+lm)*520 + k0 + lq*8);
          bf16x8 yl = *(const bf16x8*)(sUl + (mi*16+lm)*520 + k0 + lq*8);
          ao[mi] = mfma3(yh, yl, cwh, cwl, ao[mi]);
        }
      }
      __syncthreads();   // all waves done reading sUh/sUl before sT2 dump
      #pragma unroll
      for (int mi = 0; mi < 2; ++mi)
        #pragma unroll
        for (int r2 = 0; r2 < 4; ++r2)
          sT2[(mi*16 + lq*4 + r2)*260 + wave*16 + lm] = ao[mi][r2];
    }
    __syncthreads();
    ln_block(sT2, sF32, nullptr, lng, lnb, sF32, sFh, sFl, tid);
    __syncthreads();
  }

  // ================= classifier (token 31) =================
  {
    int o = tid >> 3, q = tid & 7;
    const float* fr = sF32 + 31*260 + q*32;
    const float* wr = w1 + (size_t)o*256 + q*32;
    float s = 0.f;
    #pragma unroll 8
    for (int k = 0; k < 32; ++k) s += wr[k]*fr[k];
    s += __shfl_xor(s, 1); s += __shfl_xor(s, 2); s += __shfl_xor(s, 4);
    if (q == 0) sHid[o] = fmaxf(s + b1[o], 0.f);
    __syncthreads();
    if (tid < 2) {
      float oo = b2[tid];
      #pragma unroll 8
      for (int k = 0; k < 128; ++k) oo += w2[tid*128 + k]*sHid[k];
      out[b*2 + tid] = oo;
    }
  }
}

// ---------------- launch ----------------
extern "C" void kernel_launch(void* const* d_in, const int* in_sizes, int n_in,
                              void* d_out, int out_size, void* d_ws, size_t ws_size,
                              hipStream_t stream) {
  const float* x    = (const float*)d_in[0];
  const float* ep   = (const float*)d_in[1];
  const float* ef   = (const float*)d_in[2];
  const float* ed   = (const float*)d_in[3];
  const float* plw  = (const float*)d_in[4];
  const float* plb  = (const float*)d_in[5];
  const float* piw  = (const float*)d_in[6];
  const float* pib  = (const float*)d_in[7];
  const float* fw   = (const float*)d_in[8];
  const float* fb   = (const float*)d_in[9];
  const float* tng  = (const float*)d_in[10];
  const float* tnb  = (const float*)d_in[11];
  const float* ipw  = (const float*)d_in[12];
  const float* cw   = (const float*)d_in[13];
  const float* cb   = (const float*)d_in[14];
  const float* xpw  = (const float*)d_in[15];
  const float* dpw  = (const float*)d_in[16];
  const float* dpb  = (const float*)d_in[17];
  const float* alog = (const float*)d_in[18];
  const float* dsk  = (const float*)d_in[19];
  const float* opw  = (const float*)d_in[20];
  const float* lng  = (const float*)d_in[21];
  const float* lnb  = (const float*)d_in[22];
  const float* w1   = (const float*)d_in[23];
  const float* b1   = (const float*)d_in[24];
  const float* w2   = (const float*)d_in[25];
  const float* b2   = (const float*)d_in[26];

  // workspace: split-bf16 weights only
  ushort_t* ipw_h = (ushort_t*)d_ws;
  ushort_t* ipw_l = ipw_h + (size_t)NIP;
  ushort_t* opw_h = ipw_l + (size_t)NIP;
  ushort_t* opw_l = opw_h + (size_t)NOP;
  ushort_t* xpw_h = opw_l + (size_t)NOP;
  ushort_t* xpw_l = xpw_h + (size_t)NXP;
  ushort_t* fw_h  = xpw_l + (size_t)NXP;
  ushort_t* fw_l  = fw_h  + (size_t)NFW;

  static int smem_set = 0;
  if (!smem_set) {
    hipFuncSetAttribute(reinterpret_cast<const void*>(mega_kernel),
                        hipFuncAttributeMaxDynamicSharedMemorySize, SMEM_TOTAL);
    smem_set = 1;
  }

  prep_w<<<NPREP/256, 256, 0, stream>>>(ipw, opw, xpw, fw,
      ipw_h, ipw_l, opw_h, opw_l, xpw_h, xpw_l, fw_h, fw_l);

  mega_kernel<<<BATCH, 1024, SMEM_TOTAL, stream>>>(
      x, ep, ef, ed, plw, plb, piw, pib,
      fw_h, fw_l, fb, tng, tnb,
      ipw_h, ipw_l, cw, cb, xpw_h, xpw_l,
      dpw, dpb, alog, dsk, opw_h, opw_l,
      lng, lnb, w1, b1, w2, b2, (float*)d_out);
}

// Round 7
// 496.591 us; speedup vs baseline: 1.0549x; 1.0549x over previous
//
#include <hip/hip_runtime.h>
#include <math.h>

// BlockwiseEarlyExitMamba: B=128, L=64, EXIT_POS=32 -> only t<32 matter.
// v8: v6 structure (512-thread per-batch mega-kernel) with the last persistent
// register array (sz[32]) removed structurally: Z pass writes silu(z) straight
// from MFMA fragments to a global zg buffer (no LDS roundtrip, -3 barriers),
// scan streams it back with 1-deep prefetch. No register array now lives
// across the GEMM phases -> allocator should stop spilling into the serial
// scan chain.
#define BATCH 128

using bf16x8 = __attribute__((ext_vector_type(8))) short;
using f32x4  = __attribute__((ext_vector_type(4))) float;
typedef unsigned short ushort_t;
typedef unsigned int   uint_t;

__device__ __forceinline__ float silu_f(float x) { return x / (1.f + __expf(-x)); }

__device__ __forceinline__ ushort_t bf16_rne(float f) {
  unsigned int u = __float_as_uint(f);
  u += 0x7FFFu + ((u >> 16) & 1u);
  return (ushort_t)(u >> 16);
}
__device__ __forceinline__ float bf16_to_f(ushort_t h) {
  return __uint_as_float(((unsigned int)h) << 16);
}
__device__ __forceinline__ void bf16_split(float f, ushort_t& hi, ushort_t& lo) {
  hi = bf16_rne(f);
  lo = bf16_rne(f - bf16_to_f(hi));
}

// split-bf16 3-MFMA: (ah+al)*(wh+wl) ~= ah*wh + ah*wl + al*wh  (al*wl negligible)
__device__ __forceinline__ f32x4 mfma3(bf16x8 ah, bf16x8 al, bf16x8 wh, bf16x8 wl, f32x4 acc) {
  acc = __builtin_amdgcn_mfma_f32_16x16x32_bf16(ah, wh, acc, 0, 0, 0);
  acc = __builtin_amdgcn_mfma_f32_16x16x32_bf16(ah, wl, acc, 0, 0, 0);
  acc = __builtin_amdgcn_mfma_f32_16x16x32_bf16(al, wh, acc, 0, 0, 0);
  return acc;
}

// ---------------- merged weight prep: fp32 -> hi/lo bf16 ----------------
#define NIP (4*1024*256)     // in_proj
#define NOP (4*256*512)      // out_proj
#define NXP (4*64*512)       // xproj padded 48->64 rows
#define NFW (256*160)        // fusion_w padded 136->160 cols
#define NPREP (NIP+NOP+NXP+NFW)   // 1744896 = 6816*256
__global__ __launch_bounds__(256) void prep_w(
    const float* __restrict__ ipw, const float* __restrict__ opw,
    const float* __restrict__ xpw, const float* __restrict__ fw,
    ushort_t* __restrict__ ih, ushort_t* __restrict__ il,
    ushort_t* __restrict__ oh, ushort_t* __restrict__ ol,
    ushort_t* __restrict__ xh, ushort_t* __restrict__ xl,
    ushort_t* __restrict__ fh, ushort_t* __restrict__ fl) {
  int i = blockIdx.x*256 + threadIdx.x;
  float v; ushort_t h, l;
  if (i < NIP) {
    v = ipw[i]; bf16_split(v, h, l); ih[i] = h; il[i] = l;
  } else if (i < NIP+NOP) {
    int j = i - NIP;
    v = opw[j]; bf16_split(v, h, l); oh[j] = h; ol[j] = l;
  } else if (i < NIP+NOP+NXP) {
    int j = i - (NIP+NOP);
    int lay = j >> 15;            // 64*512 = 32768
    int r = (j >> 9) & 63, c = j & 511;
    v = (r < 48) ? xpw[(size_t)lay*48*512 + r*512 + c] : 0.f;
    bf16_split(v, h, l); xh[j] = h; xl[j] = l;
  } else {
    int j = i - (NIP+NOP+NXP);
    int r = j / 160, c = j - r*160;
    v = (c < 136) ? fw[r*136 + c] : 0.f;
    bf16_split(v, h, l); fh[j] = h; fl[j] = l;
  }
}

// ---------------- LDS layout for mega kernel (bytes) ----------------
// A: sF32  f32 [32][260]                      33280   (residual feat, persistent)
// B: sFh/sFl us [32][264] x2                  33792   (feat hi/lo; aliased: sT2 f32 [32][260],
//                                                      sDbc f32 [32][68], sHid f32[128])
// C: sZT   f32 [32][524]                      67072   (pre-conv u staging; aliased:
//                                                      sUh/sUl us [32][520] x2 (u then y),
//                                                      catH/catL us [32][168] x2)
#define OFF_A 0
#define OFF_B 33280
#define OFF_C 67072
#define SMEM_TOTAL 134144

// LN of a [32][256] tile in LDS; 16 threads/row.
// Reads sIn (+resid +addv), after internal barrier writes sF32o + hi/lo bf16.
__device__ __forceinline__ void ln_block(
    const float* sIn, const float* resid, const float* addv,
    const float* __restrict__ g, const float* __restrict__ bb,
    float* sF32o, ushort_t* sFho, ushort_t* sFlo, int tid) {
  int row = tid >> 4, sub = tid & 15;
  float v[16];
  float s = 0.f;
  #pragma unroll
  for (int i = 0; i < 16; ++i) {
    int c = sub + 16*i;
    float t = sIn[row*260 + c];
    if (resid) t += resid[row*260 + c];
    if (addv)  t += addv[c];
    v[i] = t; s += t;
  }
  s += __shfl_xor(s, 1); s += __shfl_xor(s, 2); s += __shfl_xor(s, 4); s += __shfl_xor(s, 8);
  float mu = s * (1.f/256.f);
  float s2 = 0.f;
  #pragma unroll
  for (int i = 0; i < 16; ++i) { float dv = v[i]-mu; s2 += dv*dv; }
  s2 += __shfl_xor(s2, 1); s2 += __shfl_xor(s2, 2); s2 += __shfl_xor(s2, 4); s2 += __shfl_xor(s2, 8);
  float rs = rsqrtf(s2*(1.f/256.f) + 1e-5f);
  __syncthreads();              // sIn may alias sFho/sFlo: read-before, write-after
  #pragma unroll
  for (int i = 0; i < 16; ++i) {
    int c = sub + 16*i;
    float o = (v[i]-mu)*rs*g[c] + bb[c];
    sF32o[row*260 + c] = o;
    ushort_t hh, ll; bf16_split(o, hh, ll);
    sFho[row*264 + c] = hh;
    sFlo[row*264 + c] = ll;
  }
}

// ---------------- the mega kernel: tokenizer + 4 layers + classifier ----------
__global__ __launch_bounds__(512, 2) void mega_kernel(
    const float* __restrict__ x,
    const float* __restrict__ ep, const float* __restrict__ ef, const float* __restrict__ ed,
    const float* __restrict__ plw, const float* __restrict__ plb,
    const float* __restrict__ piw, const float* __restrict__ pib,
    const ushort_t* __restrict__ fw_h, const ushort_t* __restrict__ fw_l,
    const float* __restrict__ fb,
    const float* __restrict__ tng, const float* __restrict__ tnb,
    const ushort_t* __restrict__ ipw_h, const ushort_t* __restrict__ ipw_l,
    const float* __restrict__ cw, const float* __restrict__ cb,
    const ushort_t* __restrict__ xpw_h, const ushort_t* __restrict__ xpw_l,
    const float* __restrict__ dpw, const float* __restrict__ dpb,
    const float* __restrict__ alog, const float* __restrict__ dsk,
    const ushort_t* __restrict__ opw_h, const ushort_t* __restrict__ opw_l,
    const float* __restrict__ lng, const float* __restrict__ lnb,
    const float* __restrict__ w1, const float* __restrict__ b1,
    const float* __restrict__ w2, const float* __restrict__ b2,
    float* zg,                      // [128][32][512] silu(z) staging (not restrict:
                                    // written and re-read by the same block)
    float* __restrict__ out) {
  extern __shared__ __align__(16) char sm[];
  float*    sF32 = (float*)(sm + OFF_A);       // [32][260]
  ushort_t* sFh  = (ushort_t*)(sm + OFF_B);    // [32][264]
  ushort_t* sFl  = sFh + 32*264;
  float*    sT2  = (float*)(sm + OFF_B);       // [32][260] GEMM frag dump
  float*    sDbc = (float*)(sm + OFF_B);       // [32][68]
  float*    sHid = (float*)(sm + OFF_B);       // [128]
  float*    sZT  = (float*)(sm + OFF_C);       // [32][524] f32 pre-conv u staging
  ushort_t* sUh  = (ushort_t*)(sm + OFF_C);    // [32][520]  packed u hi -> later y hi
  ushort_t* sUl  = sUh + 32*520;               //            packed u lo -> later y lo
  ushort_t* catH = (ushort_t*)(sm + OFF_C);    // [32][168]
  ushort_t* catL = catH + 32*168;

  const int tid  = threadIdx.x;
  const int b    = blockIdx.x;
  const int wave = tid >> 6, lane = tid & 63;
  const int lm   = lane & 15, lq = lane >> 4;
  const int d    = tid;                        // channel owned by this thread (0..511)

  // ================= tokenizer =================
  {
    int r = tid >> 4, cl = tid & 15;
    const float* xr = x + ((size_t)b*64 + r)*5;   // L=64 stride in input
    float x0 = xr[0], x1 = xr[1], x2 = xr[2], x3 = xr[3], x4 = xr[4];
    int proto = min(max((int)x0, 0), 255);
    int flags = min(max((int)x2, 0), 63);
    int direc = min(max((int)x4, 0), 1);
    #pragma unroll
    for (int j = 0; j < 10; ++j) {
      int c = cl + 16*j;
      float v;
      if (c < 32)       v = ep[proto*32 + c];
      else if (c < 64)  v = x1*plw[c-32] + plb[c-32];
      else if (c < 96)  v = ef[flags*32 + (c-64)];
      else if (c < 128) v = x3*piw[c-96] + pib[c-96];
      else if (c < 136) v = ed[direc*8 + (c-128)];
      else              v = 0.f;
      ushort_t hh, ll; bf16_split(v, hh, ll);
      catH[r*168 + c] = hh;
      catL[r*168 + c] = ll;
    }
  }
  __syncthreads();
  // pre = cat @ fw^T (M=32, N=256, K=160); dump to sT2 (B region, free)
  {
    f32x4 acc[2][2];
    #pragma unroll
    for (int mi = 0; mi < 2; ++mi)
      #pragma unroll
      for (int nt = 0; nt < 2; ++nt) acc[mi][nt] = (f32x4){0.f,0.f,0.f,0.f};
    int nb = wave*32;
    for (int k0 = 0; k0 < 160; k0 += 32) {
      bf16x8 fAh[2], fAl[2];
      #pragma unroll
      for (int mi = 0; mi < 2; ++mi) {
        int rr = mi*16 + lm;
        fAh[mi] = *(const bf16x8*)(catH + rr*168 + k0 + lq*8);
        fAl[mi] = *(const bf16x8*)(catL + rr*168 + k0 + lq*8);
      }
      #pragma unroll
      for (int nt = 0; nt < 2; ++nt) {
        int row = nb + nt*16 + lm;
        bf16x8 wh = *(const bf16x8*)(fw_h + (size_t)row*160 + k0 + lq*8);
        bf16x8 wl = *(const bf16x8*)(fw_l + (size_t)row*160 + k0 + lq*8);
        #pragma unroll
        for (int mi = 0; mi < 2; ++mi) acc[mi][nt] = mfma3(fAh[mi], fAl[mi], wh, wl, acc[mi][nt]);
      }
    }
    #pragma unroll
    for (int mi = 0; mi < 2; ++mi)
      #pragma unroll
      for (int nt = 0; nt < 2; ++nt)
        #pragma unroll
        for (int r2 = 0; r2 < 4; ++r2)
          sT2[(mi*16 + lq*4 + r2)*260 + nb + nt*16 + lm] = acc[mi][nt][r2];
  }
  __syncthreads();
  ln_block(sT2, nullptr, fb, tng, tnb, sF32, sFh, sFl, tid);
  __syncthreads();

  // ================= 4 mamba layers =================
  #pragma unroll 1
  for (int l = 0; l < 4; ++l) {
    const ushort_t* iph = ipw_h + (size_t)l*1024*256;
    const ushort_t* ipl2= ipw_l + (size_t)l*1024*256;
    const ushort_t* xph = xpw_h + (size_t)l*64*512;
    const ushort_t* xpl = xpw_l + (size_t)l*64*512;
    const ushort_t* oph = opw_h + (size_t)l*256*512;
    const ushort_t* opl = opw_l + (size_t)l*256*512;

    // ---- Z pass: silu(feat @ ipw[512:1024]^T) -> global zg, straight from frags ----
    {
      f32x4 acc[2][4];
      #pragma unroll
      for (int mi = 0; mi < 2; ++mi)
        #pragma unroll
        for (int nt = 0; nt < 4; ++nt) acc[mi][nt] = (f32x4){0.f,0.f,0.f,0.f};
      int rowbase = 512 + wave*64;
      for (int k0 = 0; k0 < 256; k0 += 32) {
        bf16x8 fAh[2], fAl[2];
        #pragma unroll
        for (int mi = 0; mi < 2; ++mi) {
          int rr = mi*16 + lm;
          fAh[mi] = *(const bf16x8*)(sFh + rr*264 + k0 + lq*8);
          fAl[mi] = *(const bf16x8*)(sFl + rr*264 + k0 + lq*8);
        }
        #pragma unroll
        for (int nt = 0; nt < 4; ++nt) {
          int row = rowbase + nt*16 + lm;
          bf16x8 wh = *(const bf16x8*)(iph + (size_t)row*256 + k0 + lq*8);
          bf16x8 wl = *(const bf16x8*)(ipl2 + (size_t)row*256 + k0 + lq*8);
          #pragma unroll
          for (int mi = 0; mi < 2; ++mi) acc[mi][nt] = mfma3(fAh[mi], fAl[mi], wh, wl, acc[mi][nt]);
        }
      }
      float* zdst = zg + (size_t)b*32*512;
      int nb = wave*64;
      #pragma unroll
      for (int mi = 0; mi < 2; ++mi)
        #pragma unroll
        for (int nt = 0; nt < 4; ++nt)
          #pragma unroll
          for (int r2 = 0; r2 < 4; ++r2) {
            int t = mi*16 + lq*4 + r2;
            int n = nb + nt*16 + lm;
            zdst[(size_t)t*512 + n] = silu_f(acc[mi][nt][r2]);
          }
      // no barrier: U pass only re-reads sF (shared read) and region C is free
    }

    // ---- U pass: u_pre = feat @ ipw[0:512]^T -> sZT ----
    {
      f32x4 acc[2][4];
      #pragma unroll
      for (int mi = 0; mi < 2; ++mi)
        #pragma unroll
        for (int nt = 0; nt < 4; ++nt) acc[mi][nt] = (f32x4){0.f,0.f,0.f,0.f};
      int rowbase = wave*64;
      for (int k0 = 0; k0 < 256; k0 += 32) {
        bf16x8 fAh[2], fAl[2];
        #pragma unroll
        for (int mi = 0; mi < 2; ++mi) {
          int rr = mi*16 + lm;
          fAh[mi] = *(const bf16x8*)(sFh + rr*264 + k0 + lq*8);
          fAl[mi] = *(const bf16x8*)(sFl + rr*264 + k0 + lq*8);
        }
        #pragma unroll
        for (int nt = 0; nt < 4; ++nt) {
          int row = rowbase + nt*16 + lm;
          bf16x8 wh = *(const bf16x8*)(iph + (size_t)row*256 + k0 + lq*8);
          bf16x8 wl = *(const bf16x8*)(ipl2 + (size_t)row*256 + k0 + lq*8);
          #pragma unroll
          for (int mi = 0; mi < 2; ++mi) acc[mi][nt] = mfma3(fAh[mi], fAl[mi], wh, wl, acc[mi][nt]);
        }
      }
      // region C free since prev layer's outproj barrier (or tokenizer barrier)
      int nb = wave*64;
      #pragma unroll
      for (int mi = 0; mi < 2; ++mi)
        #pragma unroll
        for (int nt = 0; nt < 4; ++nt)
          #pragma unroll
          for (int r2 = 0; r2 < 4; ++r2)
            sZT[(mi*16 + lq*4 + r2)*524 + nb + nt*16 + lm] = acc[mi][nt][r2];
      __syncthreads();
      // depthwise conv (K=4, causal) + silu, per channel d; u -> packed LDS only
      {
        float xcol[32];
        #pragma unroll
        for (int t = 0; t < 32; ++t) xcol[t] = sZT[t*524 + d];
        __syncthreads();   // sZT dead; sUh/sUl may now be written
        const float* cwl = cw + (size_t)l*512*4 + (size_t)d*4;
        float w0 = cwl[0], w1c = cwl[1], w2c = cwl[2], w3 = cwl[3];
        float bias = cb[l*512 + d];
        float p1 = 0.f, p2 = 0.f, p3 = 0.f;
        #pragma unroll
        for (int t = 0; t < 32; ++t) {
          float a = bias + w0*p3 + w1c*p2 + w2c*p1 + w3*xcol[t];
          float uv = silu_f(a);
          ushort_t hh, ll; bf16_split(uv, hh, ll);
          sUh[t*520 + d] = hh;
          sUl[t*520 + d] = ll;
          p3 = p2; p2 = p1; p1 = xcol[t];
        }
      }
      __syncthreads();
    }

    // ---- xproj: dbc = u @ xpw^T (48(->64) x 512), K split across wave halves ----
    {
      f32x4 acx[2] = {(f32x4){0.f,0.f,0.f,0.f}, (f32x4){0.f,0.f,0.f,0.f}};
      int wg = wave & 3, kh = wave >> 2;
      for (int k0 = 0; k0 < 256; k0 += 32) {
        bf16x8 fAh[2], fAl[2];
        #pragma unroll
        for (int mi = 0; mi < 2; ++mi) {
          int rr = mi*16 + lm;
          fAh[mi] = *(const bf16x8*)(sUh + rr*520 + kh*256 + k0 + lq*8);
          fAl[mi] = *(const bf16x8*)(sUl + rr*520 + kh*256 + k0 + lq*8);
        }
        int row = wg*16 + lm;
        bf16x8 wh = *(const bf16x8*)(xph + (size_t)row*512 + kh*256 + k0 + lq*8);
        bf16x8 wl = *(const bf16x8*)(xpl + (size_t)row*512 + kh*256 + k0 + lq*8);
        #pragma unroll
        for (int mi = 0; mi < 2; ++mi) acx[mi] = mfma3(fAh[mi], fAl[mi], wh, wl, acx[mi]);
      }
      if (wave >= 4) {
        #pragma unroll
        for (int mi = 0; mi < 2; ++mi)
          #pragma unroll
          for (int r2 = 0; r2 < 4; ++r2)
            sDbc[(mi*16 + lq*4 + r2)*68 + wg*16 + lm] = acx[mi][r2];
      }
      __syncthreads();
      if (wave < 4) {
        #pragma unroll
        for (int mi = 0; mi < 2; ++mi)
          #pragma unroll
          for (int r2 = 0; r2 < 4; ++r2)
            sDbc[(mi*16 + lq*4 + r2)*68 + wg*16 + lm] += acx[mi][r2];
      }
      __syncthreads();
    }

    // ---- dtproj + selective scan + gate; y -> sUh/sUl in place ----
    // u read back from packed LDS; z gate streamed from zg with 1-deep prefetch
    {
      const float* dpwl = dpw + (size_t)l*512*16 + (size_t)d*16;
      f32x4 wv[4];
      #pragma unroll
      for (int k = 0; k < 4; ++k) wv[k] = *(const f32x4*)(dpwl + 4*k);
      const float* al2 = alog + (size_t)l*512*16 + (size_t)d*16;
      float cc[16], hh2[16];
      #pragma unroll
      for (int n = 0; n < 16; ++n) {
        cc[n] = -__expf(al2[n]) * 1.44269504f;
        hh2[n] = 0.f;
      }
      float bias = dpb[l*512 + d], dskv = dsk[l*512 + d];
      const float* zp = zg + (size_t)b*32*512 + d;
      float zv = zp[0];
      #pragma unroll
      for (int t = 0; t < 32; ++t) {
        float zvn = (t < 31) ? zp[(size_t)(t+1)*512] : 0.f;
        const float* rowp = sDbc + t*68;
        float raw = bias;
        #pragma unroll
        for (int k = 0; k < 4; ++k) {
          f32x4 rd = *(const f32x4*)(rowp + 4*k);
          raw += wv[k][0]*rd[0] + wv[k][1]*rd[1] + wv[k][2]*rd[2] + wv[k][3]*rd[3];
        }
        float dtv = (raw > 20.f) ? raw : __logf(1.f + __expf(raw));
        int ui = t*520 + d;
        float uv = bf16_to_f(sUh[ui]) + bf16_to_f(sUl[ui]);
        float du = dtv * uv;
        float yv = 0.f;
        #pragma unroll
        for (int k = 0; k < 4; ++k) {
          f32x4 rb = *(const f32x4*)(rowp + 16 + 4*k);
          f32x4 rc = *(const f32x4*)(rowp + 32 + 4*k);
          #pragma unroll
          for (int j = 0; j < 4; ++j) {
            int n = 4*k + j;
            float en = exp2f(dtv * cc[n]);
            hh2[n] = en*hh2[n] + du*rb[j];
            yv += hh2[n]*rc[j];
          }
        }
        float yg = (yv + uv*dskv) * zv;    // zg already holds silu(z)
        ushort_t hh, ll; bf16_split(yg, hh, ll);
        sUh[ui] = hh;     // own-column in-place overwrite (u consumed this iter)
        sUl[ui] = ll;
        zv = zvn;
      }
    }
    __syncthreads();

    // ---- out_proj (256 x 512) + residual + LN ----
    {
      f32x4 ao[2][2];
      #pragma unroll
      for (int mi = 0; mi < 2; ++mi)
        #pragma unroll
        for (int nt = 0; nt < 2; ++nt) ao[mi][nt] = (f32x4){0.f,0.f,0.f,0.f};
      int nb = wave*32;
      for (int k0 = 0; k0 < 512; k0 += 32) {
        bf16x8 yh[2], yl[2];
        #pragma unroll
        for (int mi = 0; mi < 2; ++mi) {
          int rr = mi*16 + lm;
          yh[mi] = *(const bf16x8*)(sUh + rr*520 + k0 + lq*8);
          yl[mi] = *(const bf16x8*)(sUl + rr*520 + k0 + lq*8);
        }
        #pragma unroll
        for (int nt = 0; nt < 2; ++nt) {
          int row = nb + nt*16 + lm;
          bf16x8 wh = *(const bf16x8*)(oph + (size_t)row*512 + k0 + lq*8);
          bf16x8 wl = *(const bf16x8*)(opl + (size_t)row*512 + k0 + lq*8);
          #pragma unroll
          for (int mi = 0; mi < 2; ++mi) ao[mi][nt] = mfma3(yh[mi], yl[mi], wh, wl, ao[mi][nt]);
        }
      }
      __syncthreads();   // all waves done reading sUh/sUl; sDbc readers done too
      #pragma unroll
      for (int mi = 0; mi < 2; ++mi)
        #pragma unroll
        for (int nt = 0; nt < 2; ++nt)
          #pragma unroll
          for (int r2 = 0; r2 < 4; ++r2)
            sT2[(mi*16 + lq*4 + r2)*260 + nb + nt*16 + lm] = ao[mi][nt][r2];
    }
    __syncthreads();
    ln_block(sT2, sF32, nullptr, lng, lnb, sF32, sFh, sFl, tid);
    __syncthreads();
  }

  // ================= classifier (token 31) =================
  {
    int o = tid >> 2, q = tid & 3;
    const float* fr = sF32 + 31*260;
    const float* wr = w1 + (size_t)o*256 + q*64;
    float s = 0.f;
    #pragma unroll 16
    for (int k = 0; k < 64; ++k) s += wr[k]*fr[q*64 + k];
    s += __shfl_xor(s, 1); s += __shfl_xor(s, 2);
    if (q == 0) sHid[o] = fmaxf(s + b1[o], 0.f);
    __syncthreads();
    if (tid < 2) {
      float oo = b2[tid];
      #pragma unroll 8
      for (int k = 0; k < 128; ++k) oo += w2[tid*128 + k]*sHid[k];
      out[b*2 + tid] = oo;
    }
  }
}

// ---------------- launch ----------------
extern "C" void kernel_launch(void* const* d_in, const int* in_sizes, int n_in,
                              void* d_out, int out_size, void* d_ws, size_t ws_size,
                              hipStream_t stream) {
  const float* x    = (const float*)d_in[0];
  const float* ep   = (const float*)d_in[1];
  const float* ef   = (const float*)d_in[2];
  const float* ed   = (const float*)d_in[3];
  const float* plw  = (const float*)d_in[4];
  const float* plb  = (const float*)d_in[5];
  const float* piw  = (const float*)d_in[6];
  const float* pib  = (const float*)d_in[7];
  const float* fw   = (const float*)d_in[8];
  const float* fb   = (const float*)d_in[9];
  const float* tng  = (const float*)d_in[10];
  const float* tnb  = (const float*)d_in[11];
  const float* ipw  = (const float*)d_in[12];
  const float* cw   = (const float*)d_in[13];
  const float* cb   = (const float*)d_in[14];
  const float* xpw  = (const float*)d_in[15];
  const float* dpw  = (const float*)d_in[16];
  const float* dpb  = (const float*)d_in[17];
  const float* alog = (const float*)d_in[18];
  const float* dsk  = (const float*)d_in[19];
  const float* opw  = (const float*)d_in[20];
  const float* lng  = (const float*)d_in[21];
  const float* lnb  = (const float*)d_in[22];
  const float* w1   = (const float*)d_in[23];
  const float* b1   = (const float*)d_in[24];
  const float* w2   = (const float*)d_in[25];
  const float* b2   = (const float*)d_in[26];

  // workspace: split-bf16 weights + zg staging
  ushort_t* ipw_h = (ushort_t*)d_ws;
  ushort_t* ipw_l = ipw_h + (size_t)NIP;
  ushort_t* opw_h = ipw_l + (size_t)NIP;
  ushort_t* opw_l = opw_h + (size_t)NOP;
  ushort_t* xpw_h = opw_l + (size_t)NOP;
  ushort_t* xpw_l = xpw_h + (size_t)NXP;
  ushort_t* fw_h  = xpw_l + (size_t)NXP;
  ushort_t* fw_l  = fw_h  + (size_t)NFW;
  float*    zg    = (float*)(fw_l + (size_t)NFW);   // 128*32*512 f32 = 8 MB

  static int smem_set = 0;
  if (!smem_set) {
    hipFuncSetAttribute(reinterpret_cast<const void*>(mega_kernel),
                        hipFuncAttributeMaxDynamicSharedMemorySize, SMEM_TOTAL);
    smem_set = 1;
  }

  prep_w<<<NPREP/256, 256, 0, stream>>>(ipw, opw, xpw, fw,
      ipw_h, ipw_l, opw_h, opw_l, xpw_h, xpw_l, fw_h, fw_l);

  mega_kernel<<<BATCH, 512, SMEM_TOTAL, stream>>>(
      x, ep, ef, ed, plw, plb, piw, pib,
      fw_h, fw_l, fb, tng, tnb,
      ipw_h, ipw_l, cw, cb, xpw_h, xpw_l,
      dpw, dpb, alog, dsk, opw_h, opw_l,
      lng, lnb, w1, b1, w2, b2, zg, (float*)d_out);
}

// Round 8
// 458.078 us; speedup vs baseline: 1.1436x; 1.0841x over previous
//
#include <hip/hip_runtime.h>
#include <math.h>

// BlockwiseEarlyExitMamba: B=128, L=64, EXIT_POS=32 -> only t<32 matter.
// v9: v6 base (512-thread per-batch mega-kernel, 363us) + exact
// amdgpu_waves_per_eu(2,2): LDS (134KB) already caps at 1 block/CU = 2
// waves/SIMD, but with dynamic LDS the compiler can't see that and caps
// VGPRs at 128 (targeting an impossible 2 blocks/CU), spilling ~60KB/block
// of scan state into scratch on the serial recurrence path. The exact bound
// licenses the full 256-VGPR budget at zero occupancy cost.
#define BATCH 128

using bf16x8 = __attribute__((ext_vector_type(8))) short;
using f32x4  = __attribute__((ext_vector_type(4))) float;
typedef unsigned short ushort_t;
typedef unsigned int   uint_t;

__device__ __forceinline__ float silu_f(float x) { return x / (1.f + __expf(-x)); }

__device__ __forceinline__ ushort_t bf16_rne(float f) {
  unsigned int u = __float_as_uint(f);
  u += 0x7FFFu + ((u >> 16) & 1u);
  return (ushort_t)(u >> 16);
}
__device__ __forceinline__ float bf16_to_f(ushort_t h) {
  return __uint_as_float(((unsigned int)h) << 16);
}
__device__ __forceinline__ void bf16_split(float f, ushort_t& hi, ushort_t& lo) {
  hi = bf16_rne(f);
  lo = bf16_rne(f - bf16_to_f(hi));
}

// split-bf16 3-MFMA: (ah+al)*(wh+wl) ~= ah*wh + ah*wl + al*wh  (al*wl negligible)
__device__ __forceinline__ f32x4 mfma3(bf16x8 ah, bf16x8 al, bf16x8 wh, bf16x8 wl, f32x4 acc) {
  acc = __builtin_amdgcn_mfma_f32_16x16x32_bf16(ah, wh, acc, 0, 0, 0);
  acc = __builtin_amdgcn_mfma_f32_16x16x32_bf16(ah, wl, acc, 0, 0, 0);
  acc = __builtin_amdgcn_mfma_f32_16x16x32_bf16(al, wh, acc, 0, 0, 0);
  return acc;
}

// ---------------- merged weight prep: fp32 -> hi/lo bf16 ----------------
#define NIP (4*1024*256)     // in_proj
#define NOP (4*256*512)      // out_proj
#define NXP (4*64*512)       // xproj padded 48->64 rows
#define NFW (256*160)        // fusion_w padded 136->160 cols
#define NPREP (NIP+NOP+NXP+NFW)   // 1744896 = 6816*256
__global__ __launch_bounds__(256) void prep_w(
    const float* __restrict__ ipw, const float* __restrict__ opw,
    const float* __restrict__ xpw, const float* __restrict__ fw,
    ushort_t* __restrict__ ih, ushort_t* __restrict__ il,
    ushort_t* __restrict__ oh, ushort_t* __restrict__ ol,
    ushort_t* __restrict__ xh, ushort_t* __restrict__ xl,
    ushort_t* __restrict__ fh, ushort_t* __restrict__ fl) {
  int i = blockIdx.x*256 + threadIdx.x;
  float v; ushort_t h, l;
  if (i < NIP) {
    v = ipw[i]; bf16_split(v, h, l); ih[i] = h; il[i] = l;
  } else if (i < NIP+NOP) {
    int j = i - NIP;
    v = opw[j]; bf16_split(v, h, l); oh[j] = h; ol[j] = l;
  } else if (i < NIP+NOP+NXP) {
    int j = i - (NIP+NOP);
    int lay = j >> 15;            // 64*512 = 32768
    int r = (j >> 9) & 63, c = j & 511;
    v = (r < 48) ? xpw[(size_t)lay*48*512 + r*512 + c] : 0.f;
    bf16_split(v, h, l); xh[j] = h; xl[j] = l;
  } else {
    int j = i - (NIP+NOP+NXP);
    int r = j / 160, c = j - r*160;
    v = (c < 136) ? fw[r*136 + c] : 0.f;
    bf16_split(v, h, l); fh[j] = h; fl[j] = l;
  }
}

// ---------------- LDS layout for mega kernel (bytes) ----------------
// A: sF32  f32 [32][260]                      33280   (residual feat, persistent)
// B: sFh/sFl us [32][264] x2                  33792   (feat hi/lo; aliased: sT2 f32 [32][260],
//                                                      sDbc f32 [32][68], sHid f32[128])
// C: sZT   f32 [32][524]                      67072   (staging; aliased: sUh/sUl us [32][520] x2,
//                                                      catH/catL us [32][168] x2; y overwrites u)
#define OFF_A 0
#define OFF_B 33280
#define OFF_C 67072
#define SMEM_TOTAL 134144

// LN of a [32][256] tile in LDS; 16 threads/row.
// Reads sIn (+resid +addv), after internal barrier writes sF32o + hi/lo bf16.
__device__ __forceinline__ void ln_block(
    const float* sIn, const float* resid, const float* addv,
    const float* __restrict__ g, const float* __restrict__ bb,
    float* sF32o, ushort_t* sFho, ushort_t* sFlo, int tid) {
  int row = tid >> 4, sub = tid & 15;
  float v[16];
  float s = 0.f;
  #pragma unroll
  for (int i = 0; i < 16; ++i) {
    int c = sub + 16*i;
    float t = sIn[row*260 + c];
    if (resid) t += resid[row*260 + c];
    if (addv)  t += addv[c];
    v[i] = t; s += t;
  }
  s += __shfl_xor(s, 1); s += __shfl_xor(s, 2); s += __shfl_xor(s, 4); s += __shfl_xor(s, 8);
  float mu = s * (1.f/256.f);
  float s2 = 0.f;
  #pragma unroll
  for (int i = 0; i < 16; ++i) { float dv = v[i]-mu; s2 += dv*dv; }
  s2 += __shfl_xor(s2, 1); s2 += __shfl_xor(s2, 2); s2 += __shfl_xor(s2, 4); s2 += __shfl_xor(s2, 8);
  float rs = rsqrtf(s2*(1.f/256.f) + 1e-5f);
  __syncthreads();              // sIn may alias sFho/sFlo: read-before, write-after
  #pragma unroll
  for (int i = 0; i < 16; ++i) {
    int c = sub + 16*i;
    float o = (v[i]-mu)*rs*g[c] + bb[c];
    sF32o[row*260 + c] = o;
    ushort_t hh, ll; bf16_split(o, hh, ll);
    sFho[row*264 + c] = hh;
    sFlo[row*264 + c] = ll;
  }
}

// ---------------- the mega kernel: tokenizer + 4 layers + classifier ----------
__global__ __attribute__((amdgpu_flat_work_group_size(512, 512), amdgpu_waves_per_eu(2, 2)))
void mega_kernel(
    const float* __restrict__ x,
    const float* __restrict__ ep, const float* __restrict__ ef, const float* __restrict__ ed,
    const float* __restrict__ plw, const float* __restrict__ plb,
    const float* __restrict__ piw, const float* __restrict__ pib,
    const ushort_t* __restrict__ fw_h, const ushort_t* __restrict__ fw_l,
    const float* __restrict__ fb,
    const float* __restrict__ tng, const float* __restrict__ tnb,
    const ushort_t* __restrict__ ipw_h, const ushort_t* __restrict__ ipw_l,
    const float* __restrict__ cw, const float* __restrict__ cb,
    const ushort_t* __restrict__ xpw_h, const ushort_t* __restrict__ xpw_l,
    const float* __restrict__ dpw, const float* __restrict__ dpb,
    const float* __restrict__ alog, const float* __restrict__ dsk,
    const ushort_t* __restrict__ opw_h, const ushort_t* __restrict__ opw_l,
    const float* __restrict__ lng, const float* __restrict__ lnb,
    const float* __restrict__ w1, const float* __restrict__ b1,
    const float* __restrict__ w2, const float* __restrict__ b2,
    float* __restrict__ out) {
  extern __shared__ __align__(16) char sm[];
  float*    sF32 = (float*)(sm + OFF_A);       // [32][260]
  ushort_t* sFh  = (ushort_t*)(sm + OFF_B);    // [32][264]
  ushort_t* sFl  = sFh + 32*264;
  float*    sT2  = (float*)(sm + OFF_B);       // [32][260] GEMM frag dump
  float*    sDbc = (float*)(sm + OFF_B);       // [32][68]
  float*    sHid = (float*)(sm + OFF_B);       // [128]
  float*    sZT  = (float*)(sm + OFF_C);       // [32][524] f32 staging (z, then pre-conv u)
  ushort_t* sUh  = (ushort_t*)(sm + OFF_C);    // [32][520]  packed u hi -> later y hi
  ushort_t* sUl  = sUh + 32*520;               //            packed u lo -> later y lo
  ushort_t* catH = (ushort_t*)(sm + OFF_C);    // [32][168]
  ushort_t* catL = catH + 32*168;

  const int tid  = threadIdx.x;
  const int b    = blockIdx.x;
  const int wave = tid >> 6, lane = tid & 63;
  const int lm   = lane & 15, lq = lane >> 4;
  const int d    = tid;                        // channel owned by this thread (0..511)

  // ================= tokenizer =================
  {
    int r = tid >> 4, cl = tid & 15;
    const float* xr = x + ((size_t)b*64 + r)*5;   // L=64 stride in input
    float x0 = xr[0], x1 = xr[1], x2 = xr[2], x3 = xr[3], x4 = xr[4];
    int proto = min(max((int)x0, 0), 255);
    int flags = min(max((int)x2, 0), 63);
    int direc = min(max((int)x4, 0), 1);
    #pragma unroll
    for (int j = 0; j < 10; ++j) {
      int c = cl + 16*j;
      float v;
      if (c < 32)       v = ep[proto*32 + c];
      else if (c < 64)  v = x1*plw[c-32] + plb[c-32];
      else if (c < 96)  v = ef[flags*32 + (c-64)];
      else if (c < 128) v = x3*piw[c-96] + pib[c-96];
      else if (c < 136) v = ed[direc*8 + (c-128)];
      else              v = 0.f;
      ushort_t hh, ll; bf16_split(v, hh, ll);
      catH[r*168 + c] = hh;
      catL[r*168 + c] = ll;
    }
  }
  __syncthreads();
  // pre = cat @ fw^T (M=32, N=256, K=160); dump to sT2 (B region, free)
  {
    f32x4 acc[2][2];
    #pragma unroll
    for (int mi = 0; mi < 2; ++mi)
      #pragma unroll
      for (int nt = 0; nt < 2; ++nt) acc[mi][nt] = (f32x4){0.f,0.f,0.f,0.f};
    int nb = wave*32;
    for (int k0 = 0; k0 < 160; k0 += 32) {
      bf16x8 fAh[2], fAl[2];
      #pragma unroll
      for (int mi = 0; mi < 2; ++mi) {
        int rr = mi*16 + lm;
        fAh[mi] = *(const bf16x8*)(catH + rr*168 + k0 + lq*8);
        fAl[mi] = *(const bf16x8*)(catL + rr*168 + k0 + lq*8);
      }
      #pragma unroll
      for (int nt = 0; nt < 2; ++nt) {
        int row = nb + nt*16 + lm;
        bf16x8 wh = *(const bf16x8*)(fw_h + (size_t)row*160 + k0 + lq*8);
        bf16x8 wl = *(const bf16x8*)(fw_l + (size_t)row*160 + k0 + lq*8);
        #pragma unroll
        for (int mi = 0; mi < 2; ++mi) acc[mi][nt] = mfma3(fAh[mi], fAl[mi], wh, wl, acc[mi][nt]);
      }
    }
    #pragma unroll
    for (int mi = 0; mi < 2; ++mi)
      #pragma unroll
      for (int nt = 0; nt < 2; ++nt)
        #pragma unroll
        for (int r2 = 0; r2 < 4; ++r2)
          sT2[(mi*16 + lq*4 + r2)*260 + nb + nt*16 + lm] = acc[mi][nt][r2];
  }
  __syncthreads();
  ln_block(sT2, nullptr, fb, tng, tnb, sF32, sFh, sFl, tid);
  __syncthreads();

  // ================= 4 mamba layers =================
  #pragma unroll 1
  for (int l = 0; l < 4; ++l) {
    const ushort_t* iph = ipw_h + (size_t)l*1024*256;
    const ushort_t* ipl2= ipw_l + (size_t)l*1024*256;
    const ushort_t* xph = xpw_h + (size_t)l*64*512;
    const ushort_t* xpl = xpw_l + (size_t)l*64*512;
    const ushort_t* oph = opw_h + (size_t)l*256*512;
    const ushort_t* opl = opw_l + (size_t)l*256*512;
    float sz[32];

    // ---- Z pass: z = feat @ ipw[512:1024]^T ; each wave 64 cols ----
    {
      f32x4 acc[2][4];
      #pragma unroll
      for (int mi = 0; mi < 2; ++mi)
        #pragma unroll
        for (int nt = 0; nt < 4; ++nt) acc[mi][nt] = (f32x4){0.f,0.f,0.f,0.f};
      int rowbase = 512 + wave*64;
      for (int k0 = 0; k0 < 256; k0 += 32) {
        bf16x8 fAh[2], fAl[2];
        #pragma unroll
        for (int mi = 0; mi < 2; ++mi) {
          int rr = mi*16 + lm;
          fAh[mi] = *(const bf16x8*)(sFh + rr*264 + k0 + lq*8);
          fAl[mi] = *(const bf16x8*)(sFl + rr*264 + k0 + lq*8);
        }
        #pragma unroll
        for (int nt = 0; nt < 4; ++nt) {
          int row = rowbase + nt*16 + lm;
          bf16x8 wh = *(const bf16x8*)(iph + (size_t)row*256 + k0 + lq*8);
          bf16x8 wl = *(const bf16x8*)(ipl2 + (size_t)row*256 + k0 + lq*8);
          #pragma unroll
          for (int mi = 0; mi < 2; ++mi) acc[mi][nt] = mfma3(fAh[mi], fAl[mi], wh, wl, acc[mi][nt]);
        }
      }
      __syncthreads();     // prior readers of C (prev layer outproj / tokenizer) done
      int nb = wave*64;
      #pragma unroll
      for (int mi = 0; mi < 2; ++mi)
        #pragma unroll
        for (int nt = 0; nt < 4; ++nt)
          #pragma unroll
          for (int r2 = 0; r2 < 4; ++r2)
            sZT[(mi*16 + lq*4 + r2)*524 + nb + nt*16 + lm] = acc[mi][nt][r2];
      __syncthreads();
      #pragma unroll
      for (int t = 0; t < 32; ++t) sz[t] = silu_f(sZT[t*524 + d]);
      __syncthreads();
    }

    // ---- U pass: u_pre = feat @ ipw[0:512]^T -> sZT ----
    {
      f32x4 acc[2][4];
      #pragma unroll
      for (int mi = 0; mi < 2; ++mi)
        #pragma unroll
        for (int nt = 0; nt < 4; ++nt) acc[mi][nt] = (f32x4){0.f,0.f,0.f,0.f};
      int rowbase = wave*64;
      for (int k0 = 0; k0 < 256; k0 += 32) {
        bf16x8 fAh[2], fAl[2];
        #pragma unroll
        for (int mi = 0; mi < 2; ++mi) {
          int rr = mi*16 + lm;
          fAh[mi] = *(const bf16x8*)(sFh + rr*264 + k0 + lq*8);
          fAl[mi] = *(const bf16x8*)(sFl + rr*264 + k0 + lq*8);
        }
        #pragma unroll
        for (int nt = 0; nt < 4; ++nt) {
          int row = rowbase + nt*16 + lm;
          bf16x8 wh = *(const bf16x8*)(iph + (size_t)row*256 + k0 + lq*8);
          bf16x8 wl = *(const bf16x8*)(ipl2 + (size_t)row*256 + k0 + lq*8);
          #pragma unroll
          for (int mi = 0; mi < 2; ++mi) acc[mi][nt] = mfma3(fAh[mi], fAl[mi], wh, wl, acc[mi][nt]);
        }
      }
      // sZT readers finished at the barrier ending the Z pass -> safe to overwrite
      int nb = wave*64;
      #pragma unroll
      for (int mi = 0; mi < 2; ++mi)
        #pragma unroll
        for (int nt = 0; nt < 4; ++nt)
          #pragma unroll
          for (int r2 = 0; r2 < 4; ++r2)
            sZT[(mi*16 + lq*4 + r2)*524 + nb + nt*16 + lm] = acc[mi][nt][r2];
      __syncthreads();
      // depthwise conv (K=4, causal) + silu, per channel d; u -> packed LDS only
      {
        float xcol[32];
        #pragma unroll
        for (int t = 0; t < 32; ++t) xcol[t] = sZT[t*524 + d];
        __syncthreads();   // sZT dead; sUh/sUl may now be written
        const float* cwl = cw + (size_t)l*512*4 + (size_t)d*4;
        float w0 = cwl[0], w1c = cwl[1], w2c = cwl[2], w3 = cwl[3];
        float bias = cb[l*512 + d];
        float p1 = 0.f, p2 = 0.f, p3 = 0.f;
        #pragma unroll
        for (int t = 0; t < 32; ++t) {
          float a = bias + w0*p3 + w1c*p2 + w2c*p1 + w3*xcol[t];
          float uv = silu_f(a);
          ushort_t hh, ll; bf16_split(uv, hh, ll);
          sUh[t*520 + d] = hh;
          sUl[t*520 + d] = ll;
          p3 = p2; p2 = p1; p1 = xcol[t];
        }
      }
      __syncthreads();
    }

    // ---- xproj: dbc = u @ xpw^T (48(->64) x 512), K split across wave halves ----
    {
      f32x4 acx[2] = {(f32x4){0.f,0.f,0.f,0.f}, (f32x4){0.f,0.f,0.f,0.f}};
      int wg = wave & 3, kh = wave >> 2;
      for (int k0 = 0; k0 < 256; k0 += 32) {
        bf16x8 fAh[2], fAl[2];
        #pragma unroll
        for (int mi = 0; mi < 2; ++mi) {
          int rr = mi*16 + lm;
          fAh[mi] = *(const bf16x8*)(sUh + rr*520 + kh*256 + k0 + lq*8);
          fAl[mi] = *(const bf16x8*)(sUl + rr*520 + kh*256 + k0 + lq*8);
        }
        int row = wg*16 + lm;
        bf16x8 wh = *(const bf16x8*)(xph + (size_t)row*512 + kh*256 + k0 + lq*8);
        bf16x8 wl = *(const bf16x8*)(xpl + (size_t)row*512 + kh*256 + k0 + lq*8);
        #pragma unroll
        for (int mi = 0; mi < 2; ++mi) acx[mi] = mfma3(fAh[mi], fAl[mi], wh, wl, acx[mi]);
      }
      if (wave >= 4) {
        #pragma unroll
        for (int mi = 0; mi < 2; ++mi)
          #pragma unroll
          for (int r2 = 0; r2 < 4; ++r2)
            sDbc[(mi*16 + lq*4 + r2)*68 + wg*16 + lm] = acx[mi][r2];
      }
      __syncthreads();
      if (wave < 4) {
        #pragma unroll
        for (int mi = 0; mi < 2; ++mi)
          #pragma unroll
          for (int r2 = 0; r2 < 4; ++r2)
            sDbc[(mi*16 + lq*4 + r2)*68 + wg*16 + lm] += acx[mi][r2];
      }
      __syncthreads();
    }

    // ---- dtproj + selective scan + gate; y -> sUh/sUl in place ----
    {
      const float* dpwl = dpw + (size_t)l*512*16 + (size_t)d*16;
      f32x4 wv[4];
      #pragma unroll
      for (int k = 0; k < 4; ++k) wv[k] = *(const f32x4*)(dpwl + 4*k);
      const float* al2 = alog + (size_t)l*512*16 + (size_t)d*16;
      float cc[16], hh2[16];
      #pragma unroll
      for (int n = 0; n < 16; ++n) {
        cc[n] = -__expf(al2[n]) * 1.44269504f;
        hh2[n] = 0.f;
      }
      float bias = dpb[l*512 + d], dskv = dsk[l*512 + d];
      #pragma unroll
      for (int t = 0; t < 32; ++t) {
        const float* rowp = sDbc + t*68;
        float raw = bias;
        #pragma unroll
        for (int k = 0; k < 4; ++k) {
          f32x4 rd = *(const f32x4*)(rowp + 4*k);
          raw += wv[k][0]*rd[0] + wv[k][1]*rd[1] + wv[k][2]*rd[2] + wv[k][3]*rd[3];
        }
        float dtv = (raw > 20.f) ? raw : __logf(1.f + __expf(raw));
        int ui = t*520 + d;
        float uv = bf16_to_f(sUh[ui]) + bf16_to_f(sUl[ui]);
        float du = dtv * uv;
        float yv = 0.f;
        #pragma unroll
        for (int k = 0; k < 4; ++k) {
          f32x4 rb = *(const f32x4*)(rowp + 16 + 4*k);
          f32x4 rc = *(const f32x4*)(rowp + 32 + 4*k);
          #pragma unroll
          for (int j = 0; j < 4; ++j) {
            int n = 4*k + j;
            float en = exp2f(dtv * cc[n]);
            hh2[n] = en*hh2[n] + du*rb[j];
            yv += hh2[n]*rc[j];
          }
        }
        float yg = (yv + uv*dskv) * sz[t];
        ushort_t hh, ll; bf16_split(yg, hh, ll);
        sUh[ui] = hh;     // own-column in-place overwrite (u consumed this iter)
        sUl[ui] = ll;
      }
    }
    __syncthreads();

    // ---- out_proj (256 x 512) + residual + LN ----
    {
      f32x4 ao[2][2];
      #pragma unroll
      for (int mi = 0; mi < 2; ++mi)
        #pragma unroll
        for (int nt = 0; nt < 2; ++nt) ao[mi][nt] = (f32x4){0.f,0.f,0.f,0.f};
      int nb = wave*32;
      for (int k0 = 0; k0 < 512; k0 += 32) {
        bf16x8 yh[2], yl[2];
        #pragma unroll
        for (int mi = 0; mi < 2; ++mi) {
          int rr = mi*16 + lm;
          yh[mi] = *(const bf16x8*)(sUh + rr*520 + k0 + lq*8);
          yl[mi] = *(const bf16x8*)(sUl + rr*520 + k0 + lq*8);
        }
        #pragma unroll
        for (int nt = 0; nt < 2; ++nt) {
          int row = nb + nt*16 + lm;
          bf16x8 wh = *(const bf16x8*)(oph + (size_t)row*512 + k0 + lq*8);
          bf16x8 wl = *(const bf16x8*)(opl + (size_t)row*512 + k0 + lq*8);
          #pragma unroll
          for (int mi = 0; mi < 2; ++mi) ao[mi][nt] = mfma3(yh[mi], yl[mi], wh, wl, ao[mi][nt]);
        }
      }
      __syncthreads();   // all waves done reading sUh/sUl; sDbc readers done too
      #pragma unroll
      for (int mi = 0; mi < 2; ++mi)
        #pragma unroll
        for (int nt = 0; nt < 2; ++nt)
          #pragma unroll
          for (int r2 = 0; r2 < 4; ++r2)
            sT2[(mi*16 + lq*4 + r2)*260 + nb + nt*16 + lm] = ao[mi][nt][r2];
    }
    __syncthreads();
    ln_block(sT2, sF32, nullptr, lng, lnb, sF32, sFh, sFl, tid);
    __syncthreads();
  }

  // ================= classifier (token 31) =================
  {
    int o = tid >> 2, q = tid & 3;
    const float* fr = sF32 + 31*260;
    const float* wr = w1 + (size_t)o*256 + q*64;
    float s = 0.f;
    #pragma unroll 16
    for (int k = 0; k < 64; ++k) s += wr[k]*fr[q*64 + k];
    s += __shfl_xor(s, 1); s += __shfl_xor(s, 2);
    if (q == 0) sHid[o] = fmaxf(s + b1[o], 0.f);
    __syncthreads();
    if (tid < 2) {
      float oo = b2[tid];
      #pragma unroll 8
      for (int k = 0; k < 128; ++k) oo += w2[tid*128 + k]*sHid[k];
      out[b*2 + tid] = oo;
    }
  }
}

// ---------------- launch ----------------
extern "C" void kernel_launch(void* const* d_in, const int* in_sizes, int n_in,
                              void* d_out, int out_size, void* d_ws, size_t ws_size,
                              hipStream_t stream) {
  const float* x    = (const float*)d_in[0];
  const float* ep   = (const float*)d_in[1];
  const float* ef   = (const float*)d_in[2];
  const float* ed   = (const float*)d_in[3];
  const float* plw  = (const float*)d_in[4];
  const float* plb  = (const float*)d_in[5];
  const float* piw  = (const float*)d_in[6];
  const float* pib  = (const float*)d_in[7];
  const float* fw   = (const float*)d_in[8];
  const float* fb   = (const float*)d_in[9];
  const float* tng  = (const float*)d_in[10];
  const float* tnb  = (const float*)d_in[11];
  const float* ipw  = (const float*)d_in[12];
  const float* cw   = (const float*)d_in[13];
  const float* cb   = (const float*)d_in[14];
  const float* xpw  = (const float*)d_in[15];
  const float* dpw  = (const float*)d_in[16];
  const float* dpb  = (const float*)d_in[17];
  const float* alog = (const float*)d_in[18];
  const float* dsk  = (const float*)d_in[19];
  const float* opw  = (const float*)d_in[20];
  const float* lng  = (const float*)d_in[21];
  const float* lnb  = (const float*)d_in[22];
  const float* w1   = (const float*)d_in[23];
  const float* b1   = (const float*)d_in[24];
  const float* w2   = (const float*)d_in[25];
  const float* b2   = (const float*)d_in[26];

  // workspace: split-bf16 weights only
  ushort_t* ipw_h = (ushort_t*)d_ws;
  ushort_t* ipw_l = ipw_h + (size_t)NIP;
  ushort_t* opw_h = ipw_l + (size_t)NIP;
  ushort_t* opw_l = opw_h + (size_t)NOP;
  ushort_t* xpw_h = opw_l + (size_t)NOP;
  ushort_t* xpw_l = xpw_h + (size_t)NXP;
  ushort_t* fw_h  = xpw_l + (size_t)NXP;
  ushort_t* fw_l  = fw_h  + (size_t)NFW;

  static int smem_set = 0;
  if (!smem_set) {
    hipFuncSetAttribute(reinterpret_cast<const void*>(mega_kernel),
                        hipFuncAttributeMaxDynamicSharedMemorySize, SMEM_TOTAL);
    smem_set = 1;
  }

  prep_w<<<NPREP/256, 256, 0, stream>>>(ipw, opw, xpw, fw,
      ipw_h, ipw_l, opw_h, opw_l, xpw_h, xpw_l, fw_h, fw_l);

  mega_kernel<<<BATCH, 512, SMEM_TOTAL, stream>>>(
      x, ep, ef, ed, plw, plb, piw, pib,
      fw_h, fw_l, fb, tng, tnb,
      ipw_h, ipw_l, cw, cb, xpw_h, xpw_l,
      dpw, dpb, alog, dsk, opw_h, opw_l,
      lng, lnb, w1, b1, w2, b2, (float*)d_out);
}